// Round 1
// baseline (3044.589 us; speedup 1.0000x reference)
//
#include <hip/hip_runtime.h>

constexpr int CB = 512;   // batch
constexpr int CN = 196;   // patches
constexpr int CL = 256;   // tokens
constexpr int CE = 768;   // embed
constexpr int CP = 512;   // probe dim
constexpr int CK = 98;    // top-k

__device__ __forceinline__ unsigned enc_f32(float f) {
    // order-preserving map float -> uint (greater float => greater uint)
    unsigned u = __float_as_uint(f);
    return (u & 0x80000000u) ? ~u : (u | 0x80000000u);
}

// ---------------------------------------------------------------------------
// Per-batch compaction of unmasked token indices (ascending order).
// idx[b*CL + j] = l of j-th unmasked token, cnts[b] = count.
// ---------------------------------------------------------------------------
__global__ __launch_bounds__(256) void compact_tokens(
    const int* __restrict__ amask, unsigned char* __restrict__ idx,
    int* __restrict__ cnts)
{
    __shared__ int ps[CL];
    const int b = blockIdx.x, t = threadIdx.x;
    const int m = (amask[(size_t)b * CL + t] != 0) ? 1 : 0;
    ps[t] = m;
    __syncthreads();
    for (int off = 1; off < CL; off <<= 1) {
        int add = (t >= off) ? ps[t - off] : 0;
        __syncthreads();
        ps[t] += add;
        __syncthreads();
    }
    if (m) idx[(size_t)b * CL + ps[t] - 1] = (unsigned char)t;
    if (t == CL - 1) cnts[b] = ps[t];
}

// ---------------------------------------------------------------------------
// GEMM: X(M,P) = A(M,E) @ W(E,P) + bias ; n2part[row*4+pt] = partial sum of
// squares over this block's 128 columns. M is a multiple of 64.
// Block: 256 threads, tile 64 rows x 128 cols, BK=16. Next-chunk global loads
// issued before compute (software prefetch).
// ---------------------------------------------------------------------------
__global__ __launch_bounds__(256) void gemm_proj(
    const float* __restrict__ A, const float* __restrict__ W,
    const float* __restrict__ bias, float* __restrict__ X,
    float* __restrict__ n2part)
{
    __shared__ float As[16][68];   // k-major, padded stride 68 (16B aligned)
    __shared__ float Ws[16][128];

    const int pt = blockIdx.x;           // 0..3
    const int m0 = blockIdx.y * 64;
    const int p0 = pt * 128;
    const int t  = threadIdx.x;
    const int tx = t & 15, ty = t >> 4;

    float acc[4][8];
#pragma unroll
    for (int i = 0; i < 4; ++i)
#pragma unroll
        for (int j = 0; j < 8; ++j) acc[i][j] = 0.f;

    const int arow = t >> 2;             // 0..63
    const int akc  = (t & 3) * 4;        // 0,4,8,12
    const int wrow = t >> 5;             // 0..7
    const int wcol = (t & 31) * 4;       // 0..124
    const float* Ap = A + (size_t)(m0 + arow) * CE + akc;
    const float* Wp = W + (size_t)wrow * CP + p0 + wcol;

    float4 av  = *(const float4*)(Ap);
    float4 wv0 = *(const float4*)(Wp);
    float4 wv1 = *(const float4*)(Wp + (size_t)8 * CP);

    for (int k0 = 0; k0 < CE; k0 += 16) {
        __syncthreads();
        As[akc + 0][arow] = av.x;
        As[akc + 1][arow] = av.y;
        As[akc + 2][arow] = av.z;
        As[akc + 3][arow] = av.w;
        *(float4*)&Ws[wrow][wcol]     = wv0;
        *(float4*)&Ws[wrow + 8][wcol] = wv1;
        __syncthreads();
        if (k0 + 16 < CE) {
            av  = *(const float4*)(Ap + k0 + 16);
            wv0 = *(const float4*)(Wp + (size_t)(k0 + 16) * CP);
            wv1 = *(const float4*)(Wp + (size_t)(k0 + 24) * CP);
        }
#pragma unroll
        for (int k = 0; k < 16; ++k) {
            float4 a4 = *(const float4*)&As[k][ty * 4];
            float4 b0 = *(const float4*)&Ws[k][tx * 4];
            float4 b1 = *(const float4*)&Ws[k][64 + tx * 4];
            float ar[4] = {a4.x, a4.y, a4.z, a4.w};
            float br[8] = {b0.x, b0.y, b0.z, b0.w, b1.x, b1.y, b1.z, b1.w};
#pragma unroll
            for (int i = 0; i < 4; ++i)
#pragma unroll
                for (int j = 0; j < 8; ++j)
                    acc[i][j] = fmaf(ar[i], br[j], acc[i][j]);
        }
    }

    // epilogue: bias, store X, per-row sumsq partial
    const int c0 = p0 + tx * 4;
    const int c1 = p0 + 64 + tx * 4;
    float bv[8];
#pragma unroll
    for (int j = 0; j < 4; ++j) { bv[j] = bias[c0 + j]; bv[4 + j] = bias[c1 + j]; }

    float rs[4];
#pragma unroll
    for (int i = 0; i < 4; ++i) {
        const int row = m0 + ty * 4 + i;
        float4 x0, x1;
        float s = 0.f, v;
        v = acc[i][0] + bv[0]; x0.x = v; s = fmaf(v, v, s);
        v = acc[i][1] + bv[1]; x0.y = v; s = fmaf(v, v, s);
        v = acc[i][2] + bv[2]; x0.z = v; s = fmaf(v, v, s);
        v = acc[i][3] + bv[3]; x0.w = v; s = fmaf(v, v, s);
        v = acc[i][4] + bv[4]; x1.x = v; s = fmaf(v, v, s);
        v = acc[i][5] + bv[5]; x1.y = v; s = fmaf(v, v, s);
        v = acc[i][6] + bv[6]; x1.z = v; s = fmaf(v, v, s);
        v = acc[i][7] + bv[7]; x1.w = v; s = fmaf(v, v, s);
        *(float4*)(X + (size_t)row * CP + c0) = x0;
        *(float4*)(X + (size_t)row * CP + c1) = x1;
        rs[i] = s;
    }
    __syncthreads();
    float* red = &As[0][0];   // 16*68 = 1088 floats >= 64*16
#pragma unroll
    for (int i = 0; i < 4; ++i) red[(ty * 4 + i) * 16 + tx] = rs[i];
    __syncthreads();
    if (t < 64) {
        float s = 0.f;
#pragma unroll
        for (int q = 0; q < 16; ++q) s += red[t * 16 + q];
        n2part[(size_t)(m0 + t) * 4 + pt] = s;
    }
}

// ---------------------------------------------------------------------------
// Token GEMM over COMPACTED rows: row j of batch b sources token idx[b,L,j].
// Tiles fully beyond cnts[b] exit immediately (~half the grid for p=0.5 mask).
// Ragged rows clamp to last valid (duplicate compute, never read downstream
// beyond cnt). Output layout: tfc[(b*CL + j) * CP].
// ---------------------------------------------------------------------------
__global__ __launch_bounds__(256) void gemm_proj_tok(
    const float* __restrict__ A, const float* __restrict__ W,
    const float* __restrict__ bias, const unsigned char* __restrict__ idx,
    const int* __restrict__ cnts, float* __restrict__ X,
    float* __restrict__ n2part)
{
    __shared__ float As[16][68];
    __shared__ float Ws[16][128];

    const int pt = blockIdx.x;           // 0..3
    const int m0 = blockIdx.y * 64;
    const int b  = m0 >> 8;              // CL == 256
    const int j0 = m0 & 255;
    const int cnt = cnts[b];
    if (j0 >= cnt) return;               // uniform early exit, before any sync

    const int p0 = pt * 128;
    const int t  = threadIdx.x;
    const int tx = t & 15, ty = t >> 4;

    float acc[4][8];
#pragma unroll
    for (int i = 0; i < 4; ++i)
#pragma unroll
        for (int j = 0; j < 8; ++j) acc[i][j] = 0.f;

    const int arow = t >> 2;             // 0..63
    const int akc  = (t & 3) * 4;
    const int wrow = t >> 5;
    const int wcol = (t & 31) * 4;
    const int jj = min(j0 + arow, cnt - 1);
    const int l  = idx[(size_t)b * CL + jj];
    const float* Ap = A + ((size_t)b * CL + l) * CE + akc;
    const float* Wp = W + (size_t)wrow * CP + p0 + wcol;

    float4 av  = *(const float4*)(Ap);
    float4 wv0 = *(const float4*)(Wp);
    float4 wv1 = *(const float4*)(Wp + (size_t)8 * CP);

    for (int k0 = 0; k0 < CE; k0 += 16) {
        __syncthreads();
        As[akc + 0][arow] = av.x;
        As[akc + 1][arow] = av.y;
        As[akc + 2][arow] = av.z;
        As[akc + 3][arow] = av.w;
        *(float4*)&Ws[wrow][wcol]     = wv0;
        *(float4*)&Ws[wrow + 8][wcol] = wv1;
        __syncthreads();
        if (k0 + 16 < CE) {
            av  = *(const float4*)(Ap + k0 + 16);
            wv0 = *(const float4*)(Wp + (size_t)(k0 + 16) * CP);
            wv1 = *(const float4*)(Wp + (size_t)(k0 + 24) * CP);
        }
#pragma unroll
        for (int k = 0; k < 16; ++k) {
            float4 a4 = *(const float4*)&As[k][ty * 4];
            float4 b0 = *(const float4*)&Ws[k][tx * 4];
            float4 b1 = *(const float4*)&Ws[k][64 + tx * 4];
            float ar[4] = {a4.x, a4.y, a4.z, a4.w};
            float br[8] = {b0.x, b0.y, b0.z, b0.w, b1.x, b1.y, b1.z, b1.w};
#pragma unroll
            for (int i = 0; i < 4; ++i)
#pragma unroll
                for (int j = 0; j < 8; ++j)
                    acc[i][j] = fmaf(ar[i], br[j], acc[i][j]);
        }
    }

    const int c0 = p0 + tx * 4;
    const int c1 = p0 + 64 + tx * 4;
    float bv[8];
#pragma unroll
    for (int j = 0; j < 4; ++j) { bv[j] = bias[c0 + j]; bv[4 + j] = bias[c1 + j]; }

    float rs[4];
#pragma unroll
    for (int i = 0; i < 4; ++i) {
        const int row = m0 + ty * 4 + i;
        float4 x0, x1;
        float s = 0.f, v;
        v = acc[i][0] + bv[0]; x0.x = v; s = fmaf(v, v, s);
        v = acc[i][1] + bv[1]; x0.y = v; s = fmaf(v, v, s);
        v = acc[i][2] + bv[2]; x0.z = v; s = fmaf(v, v, s);
        v = acc[i][3] + bv[3]; x0.w = v; s = fmaf(v, v, s);
        v = acc[i][4] + bv[4]; x1.x = v; s = fmaf(v, v, s);
        v = acc[i][5] + bv[5]; x1.y = v; s = fmaf(v, v, s);
        v = acc[i][6] + bv[6]; x1.z = v; s = fmaf(v, v, s);
        v = acc[i][7] + bv[7]; x1.w = v; s = fmaf(v, v, s);
        *(float4*)(X + (size_t)row * CP + c0) = x0;
        *(float4*)(X + (size_t)row * CP + c1) = x1;
        rs[i] = s;
    }
    __syncthreads();
    float* red = &As[0][0];
#pragma unroll
    for (int i = 0; i < 4; ++i) red[(ty * 4 + i) * 16 + tx] = rs[i];
    __syncthreads();
    if (t < 64) {
        float s = 0.f;
#pragma unroll
        for (int q = 0; q < 16; ++q) s += red[t * 16 + q];
        n2part[(size_t)(m0 + t) * 4 + pt] = s;
    }
}

// ---------------------------------------------------------------------------
// invn[i] = 1 / max(sqrt(sum of 4 partials), 1e-12)
// ---------------------------------------------------------------------------
__global__ void inv_norm(const float* __restrict__ n2part,
                         float* __restrict__ invn, int M)
{
    int i = blockIdx.x * 256 + threadIdx.x;
    if (i < M) {
        const float* p = n2part + (size_t)i * 4;
        float s = (p[0] + p[1]) + (p[2] + p[3]);
        float n = fmaxf(sqrtf(s), 1e-12f);
        invn[i] = 1.f / n;
    }
}

// ---------------------------------------------------------------------------
// sim over COMPACTED tokens: tile 128 pf-rows x 64 tokens, 256 threads,
// 8x4 acc per thread (split row tile: rows ty*4+(i&3)+(i>>2)*64).
// Token tiles beyond cnts[b] exit; ragged slots duplicate token cnt-1
// (max-invariant). Row max reduced via shfl_xor across the 16 tx lanes,
// combined across token tiles with atomicMax on order-preserving uints.
// grid: x = rt*4+tt (8), y = batch.
// ---------------------------------------------------------------------------
__global__ __launch_bounds__(256) void sim_max(
    const float* __restrict__ pf, const float* __restrict__ tfc,
    const float* __restrict__ invp, const float* __restrict__ invt,
    const int* __restrict__ cnts, unsigned* __restrict__ scores)
{
    __shared__ float Ps[16][132];   // [k][row 0..127]
    __shared__ float Ts[16][68];    // [k][tok 0..63]

    const int b   = blockIdx.y;
    const int rt  = blockIdx.x >> 2;   // 0..1
    const int tt  = blockIdx.x & 3;    // 0..3
    const int cnt = cnts[b];
    const int tok0 = tt * 64;
    if (tok0 >= cnt) return;           // uniform early exit
    const int r0 = rt * 128;
    const int t  = threadIdx.x;
    const int tx = t & 15, ty = t >> 4;
    const int cm1 = cnt - 1;

    const float* Pb = pf  + (size_t)b * CN * CP;
    const float* Tb = tfc + (size_t)b * CL * CP;

    // staging P: 128 rows x 16 k / 256 thr = 2 float4 each
    const int sprow = t >> 1;                 // 0..127
    const int spkc  = (t & 1) * 8;            // 0,8
    const int prow  = min(r0 + sprow, CN - 1);
    // staging T: 64 rows x 16 k / 256 thr = 1 float4 each
    const int strow = t >> 2;                 // 0..63
    const int stkc  = (t & 3) * 4;            // 0,4,8,12
    const int trow  = min(tok0 + strow, cm1);

    const float* Pp0 = Pb + (size_t)prow * CP + spkc;
    const float* Tp0 = Tb + (size_t)trow * CP + stkc;

    float acc[8][4];
#pragma unroll
    for (int i = 0; i < 8; ++i)
#pragma unroll
        for (int j = 0; j < 4; ++j) acc[i][j] = 0.f;

    float4 pa = *(const float4*)(Pp0);
    float4 pb = *(const float4*)(Pp0 + 4);
    float4 tv = *(const float4*)(Tp0);

    for (int kc = 0; kc < CP; kc += 16) {
        __syncthreads();
        Ps[spkc + 0][sprow] = pa.x; Ps[spkc + 1][sprow] = pa.y;
        Ps[spkc + 2][sprow] = pa.z; Ps[spkc + 3][sprow] = pa.w;
        Ps[spkc + 4][sprow] = pb.x; Ps[spkc + 5][sprow] = pb.y;
        Ps[spkc + 6][sprow] = pb.z; Ps[spkc + 7][sprow] = pb.w;
        Ts[stkc + 0][strow] = tv.x; Ts[stkc + 1][strow] = tv.y;
        Ts[stkc + 2][strow] = tv.z; Ts[stkc + 3][strow] = tv.w;
        __syncthreads();
        if (kc + 16 < CP) {
            pa = *(const float4*)(Pp0 + kc + 16);
            pb = *(const float4*)(Pp0 + kc + 20);
            tv = *(const float4*)(Tp0 + kc + 16);
        }
#pragma unroll
        for (int k = 0; k < 16; ++k) {
            float4 a0 = *(const float4*)&Ps[k][ty * 4];
            float4 a1 = *(const float4*)&Ps[k][64 + ty * 4];
            float4 c0 = *(const float4*)&Ts[k][tx * 4];
            float ar[8] = {a0.x, a0.y, a0.z, a0.w, a1.x, a1.y, a1.z, a1.w};
            float cr[4] = {c0.x, c0.y, c0.z, c0.w};
#pragma unroll
            for (int i = 0; i < 8; ++i)
#pragma unroll
                for (int j = 0; j < 4; ++j)
                    acc[i][j] = fmaf(ar[i], cr[j], acc[i][j]);
        }
    }

    // epilogue: scale by inverse norms, max over this thread's 4 tokens
    float it[4];
#pragma unroll
    for (int j = 0; j < 4; ++j)
        it[j] = invt[(size_t)b * CL + min(tok0 + tx * 4 + j, cm1)];

    float mx[8];
#pragma unroll
    for (int i = 0; i < 8; ++i) {
        const int row = r0 + ty * 4 + (i & 3) + ((i >> 2) << 6);
        float m = -3.402823466e38f;
        if (row < CN) {
            const float ip = invp[(size_t)b * CN + row];
#pragma unroll
            for (int j = 0; j < 4; ++j)
                m = fmaxf(m, acc[i][j] * ip * it[j]);
        }
        mx[i] = m;
    }
    // reduce across the 16 tx lanes (same ty group = contiguous lanes)
#pragma unroll
    for (int off = 1; off < 16; off <<= 1)
#pragma unroll
        for (int i = 0; i < 8; ++i)
            mx[i] = fmaxf(mx[i], __shfl_xor(mx[i], off));
    if (tx == 0) {
#pragma unroll
        for (int i = 0; i < 8; ++i) {
            const int row = r0 + ty * 4 + (i & 3) + ((i >> 2) << 6);
            if (row < CN)
                atomicMax(&scores[(size_t)b * CN + row], enc_f32(mx[i]));
        }
    }
}

// ---------------------------------------------------------------------------
// Per batch: rank each of 196 scores (desc value, asc index tie-break == jax
// top_k), select rank<K, emit selected indices in ascending index order.
// ---------------------------------------------------------------------------
__global__ __launch_bounds__(256) void topk_sel(
    const unsigned* __restrict__ scores, int* __restrict__ sel)
{
    __shared__ unsigned ky[CN];
    __shared__ int flg[CN];
    const int b = blockIdx.x, t = threadIdx.x;
    if (t < CN) ky[t] = scores[(size_t)b * CN + t];
    __syncthreads();
    int f = 0;
    if (t < CN) {
        const unsigned kt = ky[t];
        int rank = 0;
        for (int j = 0; j < CN; ++j) {
            const unsigned kj = ky[j];
            rank += (int)((kj > kt) | ((kj == kt) & (j < t)));
        }
        f = (rank < CK) ? 1 : 0;
        flg[t] = f;
    }
    __syncthreads();
    if (t < CN && f) {
        int pos = 0;
        for (int j = 0; j < t; ++j) pos += flg[j];
        sel[(size_t)b * CK + pos] = t;
    }
}

// ---------------------------------------------------------------------------
// out[b,0,:] = state[b,0,:]; out[b,1+p,:] = state[b,1+sel[b,p],:]
// one block per output row, 192 threads x float4 = 768 floats
// ---------------------------------------------------------------------------
__global__ __launch_bounds__(192) void gather_out(
    const float* __restrict__ state, const int* __restrict__ sel,
    float* __restrict__ out)
{
    const int bid = blockIdx.x;
    const int b = bid / (CK + 1);
    const int r = bid - b * (CK + 1);
    int src = 0;
    if (r > 0) src = 1 + sel[(size_t)b * CK + (r - 1)];
    const float4* s = (const float4*)(state + ((size_t)b * (CN + 1) + src) * CE);
    float4* o = (float4*)(out + ((size_t)b * (CK + 1) + r) * CE);
    o[threadIdx.x] = s[threadIdx.x];
}

extern "C" void kernel_launch(void* const* d_in, const int* in_sizes, int n_in,
                              void* d_out, int out_size, void* d_ws, size_t ws_size,
                              hipStream_t stream) {
    const float* patch = (const float*)d_in[0];   // (B,N,E)
    const float* state = (const float*)d_in[1];   // (B,N+1,E)
    const float* token = (const float*)d_in[2];   // (B,L,E)
    const float* Wpp   = (const float*)d_in[3];   // (E,P)
    const float* bpp   = (const float*)d_in[4];   // (P)
    const float* Wtp   = (const float*)d_in[5];   // (E,P)
    const float* btp   = (const float*)d_in[6];   // (P)
    const int*   amask = (const int*)d_in[7];     // (B,L)
    float* out = (float*)d_out;                   // (B,K+1,E)

    const size_t MN = (size_t)CB * CN;   // 100352
    const size_t ML = (size_t)CB * CL;   // 131072

    char* w = (char*)d_ws;
    unsigned* scores = (unsigned*)w; w += MN * 4;
    float* n2p  = (float*)w; w += MN * 4 * 4;
    float* n2t  = (float*)w; w += ML * 4 * 4;
    float* invp = (float*)w; w += MN * 4;
    float* invt = (float*)w; w += ML * 4;
    int*   sel  = (int*)w;   w += (size_t)CB * CK * 4;
    float* pf   = (float*)w; w += MN * CP * 4;
    float* tf   = (float*)w; w += ML * CP * 4;
    int*   cnts = (int*)w;   w += (size_t)CB * 4;
    unsigned char* idx = (unsigned char*)w; w += (size_t)CB * CL;

    hipMemsetAsync(scores, 0, MN * 4, stream);  // 0 == -inf sentinel in enc_f32 order

    compact_tokens<<<CB, CL, 0, stream>>>(amask, idx, cnts);
    gemm_proj<<<dim3(4, (int)(MN / 64)), 256, 0, stream>>>(patch, Wpp, bpp, pf, n2p);
    gemm_proj_tok<<<dim3(4, (int)(ML / 64)), 256, 0, stream>>>(token, Wtp, btp, idx, cnts, tf, n2t);
    inv_norm<<<(int)((MN + 255) / 256), 256, 0, stream>>>(n2p, invp, (int)MN);
    inv_norm<<<(int)((ML + 255) / 256), 256, 0, stream>>>(n2t, invt, (int)ML);
    sim_max<<<dim3(8, CB), 256, 0, stream>>>(pf, tf, invp, invt, cnts, scores);
    topk_sel<<<CB, 256, 0, stream>>>(scores, sel);
    gather_out<<<CB * (CK + 1), 192, 0, stream>>>(state, sel, out);
}